// Round 1
// baseline (1264.887 us; speedup 1.0000x reference)
//
#include <hip/hip_runtime.h>
#include <stdint.h>

typedef float  f32x4 __attribute__((ext_vector_type(4)));
typedef int    i32x4 __attribute__((ext_vector_type(4)));
typedef unsigned short u16x4 __attribute__((ext_vector_type(4)));
typedef __bf16 bf16x8 __attribute__((ext_vector_type(8)));

#define TTOK  16384
#define HDIM  512
#define NEXP  256
#define KSEL  8
#define NSLOT (TTOK*KSEL)

__device__ __forceinline__ unsigned short f2bf(float f) {
  unsigned int u = __float_as_uint(f);
  u += 0x7FFFu + ((u >> 16) & 1u);          // round-to-nearest-even
  return (unsigned short)(u >> 16);
}
__device__ __forceinline__ int swzu(int r) { return ((r >> 1) ^ (r >> 2)) & 3; }

// ---------------- cast x (f32) -> xb (bf16) ----------------
__global__ void cast_kernel(const float* __restrict__ x, unsigned short* __restrict__ xb) {
  size_t i = (size_t)(blockIdx.x * 256 + threadIdx.x) * 8;
  f32x4 a = *(const f32x4*)(x + i);
  f32x4 b = *(const f32x4*)(x + i + 4);
  u16x4 o0 = { f2bf(a[0]), f2bf(a[1]), f2bf(a[2]), f2bf(a[3]) };
  u16x4 o1 = { f2bf(b[0]), f2bf(b[1]), f2bf(b[2]), f2bf(b[3]) };
  *(u16x4*)(xb + i)     = o0;
  *(u16x4*)(xb + i + 4) = o1;
}

// ---------------- router logits: fp32 tiled GEMM (exact) ----------------
// logits[t][e] = sum_k x[t][k]*gw[e][k];  BM=64 BN=64 K=512
__global__ __launch_bounds__(256) void router_kernel(const float* __restrict__ x,
                                                     const float* __restrict__ gw,
                                                     float* __restrict__ logits) {
  __shared__ float xs[64][33];
  __shared__ float gs[64][33];
  const int tid = threadIdx.x;
  const int t0 = blockIdx.x * 64, e0 = blockIdx.y * 64;
  const int tx = tid & 15, ty = tid >> 4;
  const int lrow = tid >> 2, lg = tid & 3;
  const float* xp = x  + (size_t)(t0 + lrow) * HDIM + lg * 8;
  const float* gp = gw + (size_t)(e0 + lrow) * HDIM + lg * 8;
  float acc[4][4] = {};
  for (int k0 = 0; k0 < HDIM; k0 += 32) {
    f32x4 a = *(const f32x4*)(xp + k0);
    f32x4 b = *(const f32x4*)(xp + k0 + 4);
    f32x4 c = *(const f32x4*)(gp + k0);
    f32x4 d = *(const f32x4*)(gp + k0 + 4);
    __syncthreads();
    #pragma unroll
    for (int i = 0; i < 4; ++i) { xs[lrow][lg*8+i] = a[i]; xs[lrow][lg*8+4+i] = b[i]; }
    #pragma unroll
    for (int i = 0; i < 4; ++i) { gs[lrow][lg*8+i] = c[i]; gs[lrow][lg*8+4+i] = d[i]; }
    __syncthreads();
    #pragma unroll
    for (int k = 0; k < 32; ++k) {
      float av[4], bv[4];
      #pragma unroll
      for (int i = 0; i < 4; ++i) av[i] = xs[ty*4+i][k];
      #pragma unroll
      for (int j = 0; j < 4; ++j) bv[j] = gs[tx*4+j][k];
      #pragma unroll
      for (int i = 0; i < 4; ++i)
        #pragma unroll
        for (int j = 0; j < 4; ++j) acc[i][j] += av[i] * bv[j];
    }
  }
  #pragma unroll
  for (int i = 0; i < 4; ++i)
    #pragma unroll
    for (int j = 0; j < 4; ++j)
      logits[(size_t)(t0 + ty*4 + i) * NEXP + e0 + tx*4 + j] = acc[i][j];
}

// ---------------- top-8 + softmax + expert counts ----------------
__global__ __launch_bounds__(256) void topk_kernel(const float* __restrict__ logits,
                                                   int* __restrict__ tk_idx,
                                                   float* __restrict__ tk_w,
                                                   int* __restrict__ ctrl) {
  const int t = blockIdx.x * 4 + (threadIdx.x >> 6);
  const int lane = threadIdx.x & 63;
  const float* lp = logits + (size_t)t * NEXP;
  float v[4];
  #pragma unroll
  for (int j = 0; j < 4; ++j) v[j] = lp[lane + 64*j];
  float mval[8]; int midx[8];
  #pragma unroll
  for (int kk = 0; kk < 8; ++kk) {
    float bv = v[0]; int bj = 0;
    #pragma unroll
    for (int j = 1; j < 4; ++j) if (v[j] > bv) { bv = v[j]; bj = j; }
    unsigned int fb = __float_as_uint(bv);
    fb = (fb & 0x80000000u) ? ~fb : (fb | 0x80000000u);
    int e = lane + 64*bj;
    unsigned long long key = ((unsigned long long)fb << 32) | (unsigned int)(65535 - e);
    #pragma unroll
    for (int o = 32; o > 0; o >>= 1) {
      unsigned long long other = __shfl_xor(key, o);
      if (other > key) key = other;
    }
    int we = 65535 - (int)(key & 0xFFFFFFFFull);
    unsigned int wfb = (unsigned int)(key >> 32);
    unsigned int orig = (wfb & 0x80000000u) ? (wfb & 0x7FFFFFFFu) : ~wfb;
    mval[kk] = __uint_as_float(orig);
    midx[kk] = we;
    if (lane + 64*bj == we) v[bj] = -__builtin_inff();
  }
  float mx = mval[0];
  float w[8], sum = 0.f;
  #pragma unroll
  for (int kk = 0; kk < 8; ++kk) { w[kk] = __expf(mval[kk] - mx); sum += w[kk]; }
  float inv = 1.f / sum;
  #pragma unroll
  for (int kk = 0; kk < 8; ++kk) {
    if (lane == kk) {
      tk_idx[(size_t)t*8 + kk] = midx[kk];
      tk_w [(size_t)t*8 + kk] = w[kk] * inv;
      atomicAdd(&ctrl[midx[kk]], 1);
    }
  }
}

// ---------------- exclusive scan + tile table (serial, tiny) ----------------
__global__ void scan_kernel(int* __restrict__ ctrl, int* __restrict__ tiles) {
  if (threadIdx.x == 0 && blockIdx.x == 0) {
    int o = 0, nt = 0;
    for (int e = 0; e < NEXP; ++e) {
      ctrl[1024 + e] = o;
      int n = ctrl[e];
      for (int s = 0; s < n; s += 128) { tiles[2*nt] = e; tiles[2*nt+1] = s; ++nt; }
      o += n;
    }
    ctrl[1280] = o;
    ctrl[512]  = nt;
  }
}

// ---------------- scatter (token,slot) -> grouped order ----------------
__global__ void scatter_kernel(const int* __restrict__ tk_idx, const float* __restrict__ tk_w,
                               int* __restrict__ ctrl, int* __restrict__ slot_tok,
                               float* __restrict__ slot_w, int* __restrict__ slot_pos) {
  int i = blockIdx.x * 256 + threadIdx.x;   // < 131072
  int e = tk_idx[i];
  int pos = ctrl[1024 + e] + atomicAdd(&ctrl[256 + e], 1);
  slot_tok[pos] = i >> 3;
  slot_w[pos]   = tk_w[i];
  slot_pos[i]   = pos;
}

// ---------------- grouped/dense SwiGLU: outH = silu(X@W1)*(X@W3), bf16 ----------------
// BM=128 BN=128 Kstep=32, 4 waves (2x2), per-wave 64x64 for both u and v.
template<bool GROUPED>
__global__ __launch_bounds__(256, 2)
void swiglu_kernel(const unsigned short* __restrict__ xb,
                   const float* __restrict__ W1b, const float* __restrict__ W3b,
                   const int N,
                   const int* __restrict__ ctrl, const int* __restrict__ tiles,
                   const int* __restrict__ slot_tok,
                   unsigned short* __restrict__ outH) {
  const int tid = threadIdx.x;
  int e = 0, nrows = 128, rb;
  if (GROUPED) {
    const int nt = ctrl[512];
    if ((int)blockIdx.x >= nt) return;
    e = tiles[2*blockIdx.x];
    const int rowstart = tiles[2*blockIdx.x + 1];
    nrows = min(128, ctrl[e] - rowstart);
    rb = ctrl[1024 + e] + rowstart;
  } else {
    rb = blockIdx.x * 128;
  }
  const int ncol0 = blockIdx.y * 128;
  const size_t estride = (size_t)HDIM * N;
  const float* w1p = W1b + (GROUPED ? (size_t)e * estride : 0) + ncol0;
  const float* w3p = W3b + (GROUPED ? (size_t)e * estride : 0) + ncol0;

  __shared__ int tokArr[128];
  __shared__ unsigned short lX[128*32];
  __shared__ unsigned short lU[128*32];
  __shared__ unsigned short lV[128*32];

  if (tid < 128) {
    int r = min(tid, nrows - 1);
    tokArr[tid] = GROUPED ? slot_tok[rb + r] : (rb + tid);
  }
  __syncthreads();

  const int xrow0 = tid >> 2, xs0 = tid & 3;
  const int xrow1 = xrow0 + 64;
  const unsigned short* xptr0 = xb + (size_t)tokArr[xrow0] * HDIM + xs0 * 8;
  const unsigned short* xptr1 = xb + (size_t)tokArr[xrow1] * HDIM + xs0 * 8;
  const int kb4 = (tid >> 5) * 4;
  const int cb4 = (tid & 31) * 4;
  const float* upt = w1p + (size_t)kb4 * N + cb4;
  const float* vpt = w3p + (size_t)kb4 * N + cb4;

  const int lane = tid & 63, wid = tid >> 6;
  const int wr = (wid >> 1) * 64, wc = (wid & 1) * 64;
  const int lrow = lane & 15, lq = lane >> 4;

  f32x4 aU[4][4], aV[4][4];
  #pragma unroll
  for (int i = 0; i < 4; ++i)
    #pragma unroll
    for (int j = 0; j < 4; ++j) { f32x4 z = {0.f,0.f,0.f,0.f}; aU[i][j] = z; aV[i][j] = z; }

  i32x4 xr0, xr1; f32x4 ur[4], vr[4];
  xr0 = *(const i32x4*)(xptr0);
  xr1 = *(const i32x4*)(xptr1);
  #pragma unroll
  for (int q = 0; q < 4; ++q) {
    ur[q] = *(const f32x4*)(upt + (size_t)q * N);
    vr[q] = *(const f32x4*)(vpt + (size_t)q * N);
  }

  #pragma unroll 1
  for (int ks = 0; ks < HDIM/32; ++ks) {
    __syncthreads();
    *(i32x4*)&lX[xrow0*32 + ((xs0 ^ swzu(xrow0)) << 3)] = xr0;
    *(i32x4*)&lX[xrow1*32 + ((xs0 ^ swzu(xrow1)) << 3)] = xr1;
    #pragma unroll
    for (int j = 0; j < 4; ++j) {
      int col = cb4 + j;
      int eo = col*32 + (((kb4 >> 3) ^ swzu(col)) << 3) + (kb4 & 7);
      u16x4 tu = { f2bf(ur[0][j]), f2bf(ur[1][j]), f2bf(ur[2][j]), f2bf(ur[3][j]) };
      u16x4 tv = { f2bf(vr[0][j]), f2bf(vr[1][j]), f2bf(vr[2][j]), f2bf(vr[3][j]) };
      *(u16x4*)&lU[eo] = tu;
      *(u16x4*)&lV[eo] = tv;
    }
    __syncthreads();
    if (ks + 1 < HDIM/32) {
      int k1 = (ks + 1) * 32;
      xr0 = *(const i32x4*)(xptr0 + k1);
      xr1 = *(const i32x4*)(xptr1 + k1);
      const float* uu = upt + (size_t)k1 * N;
      const float* vv = vpt + (size_t)k1 * N;
      #pragma unroll
      for (int q = 0; q < 4; ++q) {
        ur[q] = *(const f32x4*)(uu + (size_t)q * N);
        vr[q] = *(const f32x4*)(vv + (size_t)q * N);
      }
    }
    bf16x8 af[4], bu[4], bv[4];
    #pragma unroll
    for (int i = 0; i < 4; ++i) {
      int row = wr + i*16 + lrow;
      af[i] = *(bf16x8*)&lX[row*32 + ((lq ^ swzu(row)) << 3)];
    }
    #pragma unroll
    for (int j = 0; j < 4; ++j) {
      int col = wc + j*16 + lrow;
      int off = col*32 + ((lq ^ swzu(col)) << 3);
      bu[j] = *(bf16x8*)&lU[off];
      bv[j] = *(bf16x8*)&lV[off];
    }
    #pragma unroll
    for (int i = 0; i < 4; ++i)
      #pragma unroll
      for (int j = 0; j < 4; ++j) {
        aU[i][j] = __builtin_amdgcn_mfma_f32_16x16x32_bf16(af[i], bu[j], aU[i][j], 0, 0, 0);
        aV[i][j] = __builtin_amdgcn_mfma_f32_16x16x32_bf16(af[i], bv[j], aV[i][j], 0, 0, 0);
      }
  }
  #pragma unroll
  for (int i = 0; i < 4; ++i)
    #pragma unroll
    for (int j = 0; j < 4; ++j)
      #pragma unroll
      for (int r = 0; r < 4; ++r) {
        int rl = wr + i*16 + lq*4 + r;
        if (rl < nrows) {
          int col = ncol0 + wc + j*16 + lrow;
          float uu = aU[i][j][r], vv = aV[i][j][r];
          float sg = uu / (1.0f + __expf(-uu));
          outH[(size_t)(rb + rl) * N + col] = f2bf(sg * vv);
        }
      }
}

// ---------------- grouped/dense GEMM2: out = A(bf16) @ W(f32->bf16), N=512 ----------------
template<bool GROUPED, bool F32OUT>
__global__ __launch_bounds__(256, 2)
void gemm2_kernel(const unsigned short* __restrict__ Asrc,
                  const float* __restrict__ Wb, const int K,
                  const int* __restrict__ ctrl, const int* __restrict__ tiles,
                  const float* __restrict__ slot_w,
                  unsigned short* __restrict__ outBF, float* __restrict__ outF) {
  const int tid = threadIdx.x;
  int e = 0, nrows = 128, rb;
  if (GROUPED) {
    const int nt = ctrl[512];
    if ((int)blockIdx.x >= nt) return;
    e = tiles[2*blockIdx.x];
    const int rowstart = tiles[2*blockIdx.x + 1];
    nrows = min(128, ctrl[e] - rowstart);
    rb = ctrl[1024 + e] + rowstart;
  } else {
    rb = blockIdx.x * 128;
  }
  const int ncol0 = blockIdx.y * 128;
  const float* wp = Wb + (GROUPED ? (size_t)e * K * 512 : 0) + ncol0;

  __shared__ unsigned short lX[128*32];
  __shared__ unsigned short lW[128*32];

  const int xrow0 = tid >> 2, xs0 = tid & 3;
  const int xrow1 = xrow0 + 64;
  const unsigned short* xptr0 = Asrc + (size_t)(rb + min(xrow0, nrows-1)) * K + xs0 * 8;
  const unsigned short* xptr1 = Asrc + (size_t)(rb + min(xrow1, nrows-1)) * K + xs0 * 8;
  const int kb4 = (tid >> 5) * 4;
  const int cb4 = (tid & 31) * 4;
  const float* wpt = wp + (size_t)kb4 * 512 + cb4;

  const int lane = tid & 63, wid = tid >> 6;
  const int wr = (wid >> 1) * 64, wc = (wid & 1) * 64;
  const int lrow = lane & 15, lq = lane >> 4;

  f32x4 acc[4][4];
  #pragma unroll
  for (int i = 0; i < 4; ++i)
    #pragma unroll
    for (int j = 0; j < 4; ++j) { f32x4 z = {0.f,0.f,0.f,0.f}; acc[i][j] = z; }

  i32x4 xr0, xr1; f32x4 wr4[4];
  xr0 = *(const i32x4*)(xptr0);
  xr1 = *(const i32x4*)(xptr1);
  #pragma unroll
  for (int q = 0; q < 4; ++q) wr4[q] = *(const f32x4*)(wpt + (size_t)q * 512);

  const int ksteps = K >> 5;
  #pragma unroll 1
  for (int ks = 0; ks < ksteps; ++ks) {
    __syncthreads();
    *(i32x4*)&lX[xrow0*32 + ((xs0 ^ swzu(xrow0)) << 3)] = xr0;
    *(i32x4*)&lX[xrow1*32 + ((xs0 ^ swzu(xrow1)) << 3)] = xr1;
    #pragma unroll
    for (int j = 0; j < 4; ++j) {
      int col = cb4 + j;
      int eo = col*32 + (((kb4 >> 3) ^ swzu(col)) << 3) + (kb4 & 7);
      u16x4 tw = { f2bf(wr4[0][j]), f2bf(wr4[1][j]), f2bf(wr4[2][j]), f2bf(wr4[3][j]) };
      *(u16x4*)&lW[eo] = tw;
    }
    __syncthreads();
    if (ks + 1 < ksteps) {
      int k1 = (ks + 1) * 32;
      xr0 = *(const i32x4*)(xptr0 + k1);
      xr1 = *(const i32x4*)(xptr1 + k1);
      const float* ww = wpt + (size_t)k1 * 512;
      #pragma unroll
      for (int q = 0; q < 4; ++q) wr4[q] = *(const f32x4*)(ww + (size_t)q * 512);
    }
    bf16x8 af[4], bw[4];
    #pragma unroll
    for (int i = 0; i < 4; ++i) {
      int row = wr + i*16 + lrow;
      af[i] = *(bf16x8*)&lX[row*32 + ((lq ^ swzu(row)) << 3)];
    }
    #pragma unroll
    for (int j = 0; j < 4; ++j) {
      int col = wc + j*16 + lrow;
      bw[j] = *(bf16x8*)&lW[col*32 + ((lq ^ swzu(col)) << 3)];
    }
    #pragma unroll
    for (int i = 0; i < 4; ++i)
      #pragma unroll
      for (int j = 0; j < 4; ++j)
        acc[i][j] = __builtin_amdgcn_mfma_f32_16x16x32_bf16(af[i], bw[j], acc[i][j], 0, 0, 0);
  }
  #pragma unroll
  for (int i = 0; i < 4; ++i)
    #pragma unroll
    for (int j = 0; j < 4; ++j)
      #pragma unroll
      for (int r = 0; r < 4; ++r) {
        int rl = wr + i*16 + lq*4 + r;
        if (rl < nrows) {
          int col = ncol0 + wc + j*16 + lrow;
          float v = acc[i][j][r];
          if (F32OUT) {
            outF[(size_t)(rb + rl) * 512 + col] = v;
          } else {
            outBF[(size_t)(rb + rl) * 512 + col] = f2bf(v * slot_w[rb + rl]);
          }
        }
      }
}

// ---------------- combine: out[t] += sum_k y_slot[slot_pos[t,k]] ----------------
__global__ __launch_bounds__(256) void combine_kernel(const unsigned short* __restrict__ y_slot,
                                                      const int* __restrict__ slot_pos,
                                                      float* __restrict__ out) {
  const int t = blockIdx.x;
  const int h = threadIdx.x * 2;
  const int* sp = slot_pos + (size_t)t * 8;
  float a0 = 0.f, a1 = 0.f;
  #pragma unroll
  for (int k = 0; k < 8; ++k) {
    int row = sp[k];
    unsigned int u = *(const unsigned int*)(y_slot + (size_t)row * 512 + h);
    a0 += __uint_as_float(u << 16);
    a1 += __uint_as_float(u & 0xFFFF0000u);
  }
  size_t o = (size_t)t * 512 + h;
  out[o]     += a0;
  out[o + 1] += a1;
}

// ---------------- launch ----------------
extern "C" void kernel_launch(void* const* d_in, const int* in_sizes, int n_in,
                              void* d_out, int out_size, void* d_ws, size_t ws_size,
                              hipStream_t stream) {
  (void)in_sizes; (void)n_in; (void)out_size; (void)ws_size;
  const float* x    = (const float*)d_in[0];
  const float* gate = (const float*)d_in[1];
  const float* w1   = (const float*)d_in[2];
  const float* w3   = (const float*)d_in[3];
  const float* w2   = (const float*)d_in[4];
  const float* sw1  = (const float*)d_in[5];
  const float* sw3  = (const float*)d_in[6];
  const float* sw2  = (const float*)d_in[7];
  float* out = (float*)d_out;

  char* ws = (char*)d_ws;
  int*   ctrl     = (int*)ws;                       // [0..255] counts, [256..511] fill, [512] ntiles, [1024..1280] offsets
  int*   tiles    = ctrl + 2048;                    // byte 8192, 1280*2 ints
  int*   tk_idx   = (int*)  (ws + 32768);
  float* tk_w     = (float*)(ws + 32768 + 1*524288);
  int*   slot_tok = (int*)  (ws + 32768 + 2*524288);
  float* slot_w   = (float*)(ws + 32768 + 3*524288);
  int*   slot_pos = (int*)  (ws + 32768 + 4*524288);
  float* logits   = (float*)(ws + ((size_t)4  << 20));
  unsigned short* xb     = (unsigned short*)(ws + ((size_t)20 << 20));
  unsigned short* hid    = (unsigned short*)(ws + ((size_t)36 << 20));
  unsigned short* y_slot = (unsigned short*)(ws + ((size_t)36 << 20) + (size_t)134217728);
  unsigned short* hs     = (unsigned short*)(ws + ((size_t)36 << 20) + (size_t)2 * 134217728);

  hipMemsetAsync(d_ws, 0, 2052, stream);
  cast_kernel<<<4096, 256, 0, stream>>>(x, xb);
  router_kernel<<<dim3(256, 4), 256, 0, stream>>>(x, gate, logits);
  topk_kernel<<<4096, 256, 0, stream>>>(logits, tk_idx, tk_w, ctrl);
  scan_kernel<<<1, 64, 0, stream>>>(ctrl, tiles);
  scatter_kernel<<<512, 256, 0, stream>>>(tk_idx, tk_w, ctrl, slot_tok, slot_w, slot_pos);
  swiglu_kernel<true><<<dim3(1280, 4), 256, 0, stream>>>(xb, w1, w3, 512, ctrl, tiles, slot_tok, hid);
  gemm2_kernel<true, false><<<dim3(1280, 4), 256, 0, stream>>>(hid, w2, 512, ctrl, tiles, slot_w, y_slot, nullptr);
  swiglu_kernel<false><<<dim3(128, 11), 256, 0, stream>>>(xb, sw1, sw3, 1408, ctrl, tiles, slot_tok, hs);
  gemm2_kernel<false, true><<<dim3(128, 4), 256, 0, stream>>>(hs, sw2, 1408, ctrl, tiles, slot_w, nullptr, out);
  combine_kernel<<<16384, 256, 0, stream>>>(y_slot, slot_pos, out);
}

// Round 2
// 1012.132 us; speedup vs baseline: 1.2497x; 1.2497x over previous
//
#include <hip/hip_runtime.h>
#include <stdint.h>

typedef float  f32x4 __attribute__((ext_vector_type(4)));
typedef int    i32x4 __attribute__((ext_vector_type(4)));
typedef __bf16 bf16x4v __attribute__((ext_vector_type(4)));
typedef __bf16 bf16x8 __attribute__((ext_vector_type(8)));

#define TTOK  16384
#define HDIM  512
#define NEXP  256
#define KSEL  8

__device__ __forceinline__ int swzu(int r) { return ((r >> 1) ^ (r >> 2)) & 3; }

// chunked XCD swizzle: logical block b runs on XCD (b / (G/8)) — grid must be %8==0
__device__ __forceinline__ int xcdmap(int orig, int G) {
  int q = G >> 3;
  return (orig & 7) * q + (orig >> 3);
}

// ---------------- cast x (f32) -> xb (bf16) ----------------
__global__ void cast_kernel(const float* __restrict__ x, unsigned short* __restrict__ xb) {
  size_t i = (size_t)(blockIdx.x * 256 + threadIdx.x) * 8;
  f32x4 a = *(const f32x4*)(x + i);
  f32x4 b = *(const f32x4*)(x + i + 4);
  bf16x4v o0 = { (__bf16)a[0], (__bf16)a[1], (__bf16)a[2], (__bf16)a[3] };
  bf16x4v o1 = { (__bf16)b[0], (__bf16)b[1], (__bf16)b[2], (__bf16)b[3] };
  *(bf16x4v*)((__bf16*)xb + i)     = o0;
  *(bf16x4v*)((__bf16*)xb + i + 4) = o1;
}

// ---------------- router logits: fp32 tiled GEMM (exact) ----------------
__global__ __launch_bounds__(256) void router_kernel(const float* __restrict__ x,
                                                     const float* __restrict__ gw,
                                                     float* __restrict__ logits) {
  __shared__ float xs[64][33];
  __shared__ float gs[64][33];
  const int tid = threadIdx.x;
  const int t0 = blockIdx.x * 64, e0 = blockIdx.y * 64;
  const int tx = tid & 15, ty = tid >> 4;
  const int lrow = tid >> 2, lg = tid & 3;
  const float* xp = x  + (size_t)(t0 + lrow) * HDIM + lg * 8;
  const float* gp = gw + (size_t)(e0 + lrow) * HDIM + lg * 8;
  float acc[4][4] = {};
  for (int k0 = 0; k0 < HDIM; k0 += 32) {
    f32x4 a = *(const f32x4*)(xp + k0);
    f32x4 b = *(const f32x4*)(xp + k0 + 4);
    f32x4 c = *(const f32x4*)(gp + k0);
    f32x4 d = *(const f32x4*)(gp + k0 + 4);
    __syncthreads();
    #pragma unroll
    for (int i = 0; i < 4; ++i) { xs[lrow][lg*8+i] = a[i]; xs[lrow][lg*8+4+i] = b[i]; }
    #pragma unroll
    for (int i = 0; i < 4; ++i) { gs[lrow][lg*8+i] = c[i]; gs[lrow][lg*8+4+i] = d[i]; }
    __syncthreads();
    #pragma unroll
    for (int k = 0; k < 32; ++k) {
      float av[4], bv[4];
      #pragma unroll
      for (int i = 0; i < 4; ++i) av[i] = xs[ty*4+i][k];
      #pragma unroll
      for (int j = 0; j < 4; ++j) bv[j] = gs[tx*4+j][k];
      #pragma unroll
      for (int i = 0; i < 4; ++i)
        #pragma unroll
        for (int j = 0; j < 4; ++j) acc[i][j] += av[i] * bv[j];
    }
  }
  #pragma unroll
  for (int i = 0; i < 4; ++i)
    #pragma unroll
    for (int j = 0; j < 4; ++j)
      logits[(size_t)(t0 + ty*4 + i) * NEXP + e0 + tx*4 + j] = acc[i][j];
}

// ---------------- top-8 + softmax + expert counts ----------------
__global__ __launch_bounds__(256) void topk_kernel(const float* __restrict__ logits,
                                                   int* __restrict__ tk_idx,
                                                   float* __restrict__ tk_w,
                                                   int* __restrict__ ctrl) {
  const int t = blockIdx.x * 4 + (threadIdx.x >> 6);
  const int lane = threadIdx.x & 63;
  const float* lp = logits + (size_t)t * NEXP;
  float v[4];
  #pragma unroll
  for (int j = 0; j < 4; ++j) v[j] = lp[lane + 64*j];
  float mval[8]; int midx[8];
  #pragma unroll
  for (int kk = 0; kk < 8; ++kk) {
    float bv = v[0]; int bj = 0;
    #pragma unroll
    for (int j = 1; j < 4; ++j) if (v[j] > bv) { bv = v[j]; bj = j; }
    unsigned int fb = __float_as_uint(bv);
    fb = (fb & 0x80000000u) ? ~fb : (fb | 0x80000000u);
    int e = lane + 64*bj;
    unsigned long long key = ((unsigned long long)fb << 32) | (unsigned int)(65535 - e);
    #pragma unroll
    for (int o = 32; o > 0; o >>= 1) {
      unsigned long long other = __shfl_xor(key, o);
      if (other > key) key = other;
    }
    int we = 65535 - (int)(key & 0xFFFFFFFFull);
    unsigned int wfb = (unsigned int)(key >> 32);
    unsigned int orig = (wfb & 0x80000000u) ? (wfb & 0x7FFFFFFFu) : ~wfb;
    mval[kk] = __uint_as_float(orig);
    midx[kk] = we;
    if (lane + 64*bj == we) v[bj] = -__builtin_inff();
  }
  float mx = mval[0];
  float w[8], sum = 0.f;
  #pragma unroll
  for (int kk = 0; kk < 8; ++kk) { w[kk] = __expf(mval[kk] - mx); sum += w[kk]; }
  float inv = 1.f / sum;
  #pragma unroll
  for (int kk = 0; kk < 8; ++kk) {
    if (lane == kk) {
      tk_idx[(size_t)t*8 + kk] = midx[kk];
      tk_w [(size_t)t*8 + kk] = w[kk] * inv;
      atomicAdd(&ctrl[midx[kk]], 1);
    }
  }
}

// ---------------- parallel scan + tile table ----------------
__global__ __launch_bounds__(256) void scan_kernel(int* __restrict__ ctrl, int* __restrict__ tiles) {
  __shared__ int sn[256], st[256];
  const int e = threadIdx.x;
  const int n = ctrl[e];
  const int tc = (n + 127) >> 7;
  sn[e] = n; st[e] = tc;
  __syncthreads();
  for (int d = 1; d < 256; d <<= 1) {
    int a = 0, b = 0;
    if (e >= d) { a = sn[e - d]; b = st[e - d]; }
    __syncthreads();
    sn[e] += a; st[e] += b;
    __syncthreads();
  }
  ctrl[1024 + e] = sn[e] - n;
  const int tbase = st[e] - tc;
  for (int i = 0; i < tc; ++i) { tiles[2*(tbase+i)] = e; tiles[2*(tbase+i)+1] = i << 7; }
  if (e == 255) { ctrl[512] = st[255]; ctrl[1280] = sn[255]; }
}

// ---------------- scatter (token,slot) -> grouped order ----------------
__global__ void scatter_kernel(const int* __restrict__ tk_idx, const float* __restrict__ tk_w,
                               int* __restrict__ ctrl, int* __restrict__ slot_tok,
                               float* __restrict__ slot_w, int* __restrict__ slot_pos) {
  int i = blockIdx.x * 256 + threadIdx.x;
  int e = tk_idx[i];
  int pos = ctrl[1024 + e] + atomicAdd(&ctrl[256 + e], 1);
  slot_tok[pos] = i >> 3;
  slot_w[pos]   = tk_w[i];
  slot_pos[i]   = pos;
}

// ---------------- grouped/dense SwiGLU ----------------
// 1D swizzled grid. GROUPED: b = tile*4 + colblk (N=512). DENSE: b = colblk*128 + rowtile.
template<bool GROUPED>
__global__ __launch_bounds__(256, 2)
void swiglu_kernel(const unsigned short* __restrict__ xb,
                   const float* __restrict__ W1b, const float* __restrict__ W3b,
                   const int N,
                   const int* __restrict__ ctrl, const int* __restrict__ tiles,
                   const int* __restrict__ slot_tok,
                   unsigned short* __restrict__ outH) {
  const int tid = threadIdx.x;
  const int b = xcdmap(blockIdx.x, gridDim.x);
  int e = 0, nrows = 128, rb, ncol0;
  if (GROUPED) {
    const int tIdx = b >> 2;
    ncol0 = (b & 3) << 7;
    if (tIdx >= ctrl[512]) return;
    e = tiles[2*tIdx];
    const int rowstart = tiles[2*tIdx + 1];
    nrows = min(128, ctrl[e] - rowstart);
    rb = ctrl[1024 + e] + rowstart;
  } else {
    ncol0 = (b >> 7) << 7;
    rb = (b & 127) << 7;
  }
  const size_t estride = (size_t)HDIM * N;
  const float* w1p = W1b + (GROUPED ? (size_t)e * estride : 0) + ncol0;
  const float* w3p = W3b + (GROUPED ? (size_t)e * estride : 0) + ncol0;

  __shared__ int tokArr[128];
  __shared__ unsigned short lX[128*32];
  __shared__ unsigned short lU[128*32];
  __shared__ unsigned short lV[128*32];

  if (tid < 128) {
    int r = min(tid, nrows - 1);
    tokArr[tid] = GROUPED ? slot_tok[rb + r] : (rb + tid);
  }
  __syncthreads();

  const int xrow0 = tid >> 2, xs0 = tid & 3;
  const int xrow1 = xrow0 + 64;
  const unsigned short* xptr0 = xb + (size_t)tokArr[xrow0] * HDIM + xs0 * 8;
  const unsigned short* xptr1 = xb + (size_t)tokArr[xrow1] * HDIM + xs0 * 8;
  const int kb4 = (tid >> 5) * 4;
  const int cb4 = (tid & 31) * 4;
  const float* upt = w1p + (size_t)kb4 * N + cb4;
  const float* vpt = w3p + (size_t)kb4 * N + cb4;

  const int lane = tid & 63, wid = tid >> 6;
  const int wr = (wid >> 1) * 64, wc = (wid & 1) * 64;
  const int lrow = lane & 15, lq = lane >> 4;

  f32x4 aU[4][4], aV[4][4];
  #pragma unroll
  for (int i = 0; i < 4; ++i)
    #pragma unroll
    for (int j = 0; j < 4; ++j) { f32x4 z = {0.f,0.f,0.f,0.f}; aU[i][j] = z; aV[i][j] = z; }

  i32x4 xr0, xr1; f32x4 ur[4], vr[4];
  xr0 = *(const i32x4*)(xptr0);
  xr1 = *(const i32x4*)(xptr1);
  #pragma unroll
  for (int q = 0; q < 4; ++q) {
    ur[q] = *(const f32x4*)(upt + (size_t)q * N);
    vr[q] = *(const f32x4*)(vpt + (size_t)q * N);
  }

  #pragma unroll 1
  for (int ks = 0; ks < HDIM/32; ++ks) {
    __syncthreads();
    *(i32x4*)&lX[xrow0*32 + ((xs0 ^ swzu(xrow0)) << 3)] = xr0;
    *(i32x4*)&lX[xrow1*32 + ((xs0 ^ swzu(xrow1)) << 3)] = xr1;
    #pragma unroll
    for (int j = 0; j < 4; ++j) {
      int col = cb4 + j;
      int eo = col*32 + (((kb4 >> 3) ^ swzu(col)) << 3) + (kb4 & 7);
      bf16x4v tu = { (__bf16)ur[0][j], (__bf16)ur[1][j], (__bf16)ur[2][j], (__bf16)ur[3][j] };
      bf16x4v tv = { (__bf16)vr[0][j], (__bf16)vr[1][j], (__bf16)vr[2][j], (__bf16)vr[3][j] };
      *(bf16x4v*)&lU[eo] = tu;
      *(bf16x4v*)&lV[eo] = tv;
    }
    __syncthreads();
    if (ks + 1 < HDIM/32) {
      int k1 = (ks + 1) * 32;
      xr0 = *(const i32x4*)(xptr0 + k1);
      xr1 = *(const i32x4*)(xptr1 + k1);
      const float* uu = upt + (size_t)k1 * N;
      const float* vv = vpt + (size_t)k1 * N;
      #pragma unroll
      for (int q = 0; q < 4; ++q) {
        ur[q] = *(const f32x4*)(uu + (size_t)q * N);
        vr[q] = *(const f32x4*)(vv + (size_t)q * N);
      }
    }
    bf16x8 af[4], bu[4], bv[4];
    #pragma unroll
    for (int i = 0; i < 4; ++i) {
      int row = wr + i*16 + lrow;
      af[i] = *(bf16x8*)&lX[row*32 + ((lq ^ swzu(row)) << 3)];
    }
    #pragma unroll
    for (int j = 0; j < 4; ++j) {
      int col = wc + j*16 + lrow;
      int off = col*32 + ((lq ^ swzu(col)) << 3);
      bu[j] = *(bf16x8*)&lU[off];
      bv[j] = *(bf16x8*)&lV[off];
    }
    #pragma unroll
    for (int i = 0; i < 4; ++i)
      #pragma unroll
      for (int j = 0; j < 4; ++j) {
        aU[i][j] = __builtin_amdgcn_mfma_f32_16x16x32_bf16(af[i], bu[j], aU[i][j], 0, 0, 0);
        aV[i][j] = __builtin_amdgcn_mfma_f32_16x16x32_bf16(af[i], bv[j], aV[i][j], 0, 0, 0);
      }
  }
  #pragma unroll
  for (int i = 0; i < 4; ++i)
    #pragma unroll
    for (int j = 0; j < 4; ++j)
      #pragma unroll
      for (int r = 0; r < 4; ++r) {
        int rl = wr + i*16 + lq*4 + r;
        if (rl < nrows) {
          int col = ncol0 + wc + j*16 + lrow;
          float uu = aU[i][j][r], vv = aV[i][j][r];
          float sg = uu / (1.0f + __expf(-uu));
          ((__bf16*)outH)[(size_t)(rb + rl) * N + col] = (__bf16)(sg * vv);
        }
      }
}

// ---------------- grouped/dense GEMM2: out = A(bf16) @ W(f32->bf16), N=512 ----------------
template<bool GROUPED, bool F32OUT>
__global__ __launch_bounds__(256, 2)
void gemm2_kernel(const unsigned short* __restrict__ Asrc,
                  const float* __restrict__ Wb, const int K,
                  const int* __restrict__ ctrl, const int* __restrict__ tiles,
                  const float* __restrict__ slot_w,
                  unsigned short* __restrict__ outBF, float* __restrict__ outF) {
  const int tid = threadIdx.x;
  const int b = xcdmap(blockIdx.x, gridDim.x);
  int e = 0, nrows = 128, rb, ncol0;
  if (GROUPED) {
    const int tIdx = b >> 2;
    ncol0 = (b & 3) << 7;
    if (tIdx >= ctrl[512]) return;
    e = tiles[2*tIdx];
    const int rowstart = tiles[2*tIdx + 1];
    nrows = min(128, ctrl[e] - rowstart);
    rb = ctrl[1024 + e] + rowstart;
  } else {
    ncol0 = (b >> 7) << 7;
    rb = (b & 127) << 7;
  }
  const float* wp = Wb + (GROUPED ? (size_t)e * K * 512 : 0) + ncol0;

  __shared__ unsigned short lX[128*32];
  __shared__ unsigned short lW[128*32];

  const int xrow0 = tid >> 2, xs0 = tid & 3;
  const int xrow1 = xrow0 + 64;
  const unsigned short* xptr0 = Asrc + (size_t)(rb + min(xrow0, nrows-1)) * K + xs0 * 8;
  const unsigned short* xptr1 = Asrc + (size_t)(rb + min(xrow1, nrows-1)) * K + xs0 * 8;
  const int kb4 = (tid >> 5) * 4;
  const int cb4 = (tid & 31) * 4;
  const float* wpt = wp + (size_t)kb4 * 512 + cb4;

  const int lane = tid & 63, wid = tid >> 6;
  const int wr = (wid >> 1) * 64, wc = (wid & 1) * 64;
  const int lrow = lane & 15, lq = lane >> 4;

  f32x4 acc[4][4];
  #pragma unroll
  for (int i = 0; i < 4; ++i)
    #pragma unroll
    for (int j = 0; j < 4; ++j) { f32x4 z = {0.f,0.f,0.f,0.f}; acc[i][j] = z; }

  i32x4 xr0, xr1; f32x4 wr4[4];
  xr0 = *(const i32x4*)(xptr0);
  xr1 = *(const i32x4*)(xptr1);
  #pragma unroll
  for (int q = 0; q < 4; ++q) wr4[q] = *(const f32x4*)(wpt + (size_t)q * 512);

  const int ksteps = K >> 5;
  #pragma unroll 1
  for (int ks = 0; ks < ksteps; ++ks) {
    __syncthreads();
    *(i32x4*)&lX[xrow0*32 + ((xs0 ^ swzu(xrow0)) << 3)] = xr0;
    *(i32x4*)&lX[xrow1*32 + ((xs0 ^ swzu(xrow1)) << 3)] = xr1;
    #pragma unroll
    for (int j = 0; j < 4; ++j) {
      int col = cb4 + j;
      int eo = col*32 + (((kb4 >> 3) ^ swzu(col)) << 3) + (kb4 & 7);
      bf16x4v tw = { (__bf16)wr4[0][j], (__bf16)wr4[1][j], (__bf16)wr4[2][j], (__bf16)wr4[3][j] };
      *(bf16x4v*)&lW[eo] = tw;
    }
    __syncthreads();
    if (ks + 1 < ksteps) {
      int k1 = (ks + 1) * 32;
      xr0 = *(const i32x4*)(xptr0 + k1);
      xr1 = *(const i32x4*)(xptr1 + k1);
      const float* ww = wpt + (size_t)k1 * 512;
      #pragma unroll
      for (int q = 0; q < 4; ++q) wr4[q] = *(const f32x4*)(ww + (size_t)q * 512);
    }
    bf16x8 af[4], bw[4];
    #pragma unroll
    for (int i = 0; i < 4; ++i) {
      int row = wr + i*16 + lrow;
      af[i] = *(bf16x8*)&lX[row*32 + ((lq ^ swzu(row)) << 3)];
    }
    #pragma unroll
    for (int j = 0; j < 4; ++j) {
      int col = wc + j*16 + lrow;
      bw[j] = *(bf16x8*)&lW[col*32 + ((lq ^ swzu(col)) << 3)];
    }
    #pragma unroll
    for (int i = 0; i < 4; ++i)
      #pragma unroll
      for (int j = 0; j < 4; ++j)
        acc[i][j] = __builtin_amdgcn_mfma_f32_16x16x32_bf16(af[i], bw[j], acc[i][j], 0, 0, 0);
  }
  #pragma unroll
  for (int i = 0; i < 4; ++i)
    #pragma unroll
    for (int j = 0; j < 4; ++j)
      #pragma unroll
      for (int r = 0; r < 4; ++r) {
        int rl = wr + i*16 + lq*4 + r;
        if (rl < nrows) {
          int col = ncol0 + wc + j*16 + lrow;
          float v = acc[i][j][r];
          if (F32OUT) {
            outF[(size_t)(rb + rl) * 512 + col] = v;
          } else {
            ((__bf16*)outBF)[(size_t)(rb + rl) * 512 + col] = (__bf16)(v * slot_w[rb + rl]);
          }
        }
      }
}

// ---------------- combine ----------------
__global__ __launch_bounds__(256) void combine_kernel(const unsigned short* __restrict__ y_slot,
                                                      const int* __restrict__ slot_pos,
                                                      float* __restrict__ out) {
  const int t = blockIdx.x;
  const int h = threadIdx.x * 2;
  const int* sp = slot_pos + (size_t)t * 8;
  float a0 = 0.f, a1 = 0.f;
  #pragma unroll
  for (int k = 0; k < 8; ++k) {
    int row = sp[k];
    unsigned int u = *(const unsigned int*)(y_slot + (size_t)row * 512 + h);
    a0 += __uint_as_float(u << 16);
    a1 += __uint_as_float(u & 0xFFFF0000u);
  }
  size_t o = (size_t)t * 512 + h;
  out[o]     += a0;
  out[o + 1] += a1;
}

// ---------------- launch ----------------
extern "C" void kernel_launch(void* const* d_in, const int* in_sizes, int n_in,
                              void* d_out, int out_size, void* d_ws, size_t ws_size,
                              hipStream_t stream) {
  (void)in_sizes; (void)n_in; (void)out_size; (void)ws_size;
  const float* x    = (const float*)d_in[0];
  const float* gate = (const float*)d_in[1];
  const float* w1   = (const float*)d_in[2];
  const float* w3   = (const float*)d_in[3];
  const float* w2   = (const float*)d_in[4];
  const float* sw1  = (const float*)d_in[5];
  const float* sw3  = (const float*)d_in[6];
  const float* sw2  = (const float*)d_in[7];
  float* out = (float*)d_out;

  char* ws = (char*)d_ws;
  int*   ctrl     = (int*)ws;
  int*   tiles    = ctrl + 2048;
  int*   tk_idx   = (int*)  (ws + 32768);
  float* tk_w     = (float*)(ws + 32768 + 1*524288);
  int*   slot_tok = (int*)  (ws + 32768 + 2*524288);
  float* slot_w   = (float*)(ws + 32768 + 3*524288);
  int*   slot_pos = (int*)  (ws + 32768 + 4*524288);
  float* logits   = (float*)(ws + ((size_t)4  << 20));
  unsigned short* xb     = (unsigned short*)(ws + ((size_t)20 << 20));
  unsigned short* hid    = (unsigned short*)(ws + ((size_t)36 << 20));
  unsigned short* y_slot = (unsigned short*)(ws + ((size_t)36 << 20) + (size_t)134217728);
  unsigned short* hs     = (unsigned short*)(ws + ((size_t)36 << 20) + (size_t)2 * 134217728);

  hipMemsetAsync(d_ws, 0, 2052, stream);
  cast_kernel<<<4096, 256, 0, stream>>>(x, xb);
  router_kernel<<<dim3(256, 4), 256, 0, stream>>>(x, gate, logits);
  topk_kernel<<<4096, 256, 0, stream>>>(logits, tk_idx, tk_w, ctrl);
  scan_kernel<<<1, 256, 0, stream>>>(ctrl, tiles);
  scatter_kernel<<<512, 256, 0, stream>>>(tk_idx, tk_w, ctrl, slot_tok, slot_w, slot_pos);
  swiglu_kernel<true><<<5120, 256, 0, stream>>>(xb, w1, w3, 512, ctrl, tiles, slot_tok, hid);
  gemm2_kernel<true, false><<<5120, 256, 0, stream>>>(hid, w2, 512, ctrl, tiles, slot_w, y_slot, nullptr);
  swiglu_kernel<false><<<1408, 256, 0, stream>>>(xb, sw1, sw3, 1408, ctrl, tiles, slot_tok, hs);
  gemm2_kernel<false, true><<<512, 256, 0, stream>>>(hs, sw2, 1408, ctrl, tiles, slot_w, nullptr, out);
  combine_kernel<<<16384, 256, 0, stream>>>(y_slot, slot_pos, out);
}

// Round 3
// 967.199 us; speedup vs baseline: 1.3078x; 1.0465x over previous
//
#include <hip/hip_runtime.h>
#include <stdint.h>

typedef float  f32x4 __attribute__((ext_vector_type(4)));
typedef int    i32x4 __attribute__((ext_vector_type(4)));
typedef __bf16 bf16x4v __attribute__((ext_vector_type(4)));
typedef __bf16 bf16x8 __attribute__((ext_vector_type(8)));

#define TTOK  16384
#define HDIM  512
#define NEXP  256
#define KSEL  8

__device__ __forceinline__ int swzu(int r) { return ((r >> 1) ^ (r >> 2)) & 3; }

// chunked XCD swizzle: logical block b runs on XCD (b / (G/8)) — grid must be %8==0
__device__ __forceinline__ int xcdmap(int orig, int G) {
  int q = G >> 3;
  return (orig & 7) * q + (orig >> 3);
}

// ---------------- cast x (f32) -> xb (bf16) ----------------
__global__ void cast_kernel(const float* __restrict__ x, unsigned short* __restrict__ xb) {
  size_t i = (size_t)(blockIdx.x * 256 + threadIdx.x) * 8;
  f32x4 a = *(const f32x4*)(x + i);
  f32x4 b = *(const f32x4*)(x + i + 4);
  bf16x4v o0 = { (__bf16)a[0], (__bf16)a[1], (__bf16)a[2], (__bf16)a[3] };
  bf16x4v o1 = { (__bf16)b[0], (__bf16)b[1], (__bf16)b[2], (__bf16)b[3] };
  *(bf16x4v*)((__bf16*)xb + i)     = o0;
  *(bf16x4v*)((__bf16*)xb + i + 4) = o1;
}

// ---------------- router logits: fp32 tiled GEMM (exact) ----------------
__global__ __launch_bounds__(256) void router_kernel(const float* __restrict__ x,
                                                     const float* __restrict__ gw,
                                                     float* __restrict__ logits) {
  __shared__ float xs[64][33];
  __shared__ float gs[64][33];
  const int tid = threadIdx.x;
  const int t0 = blockIdx.x * 64, e0 = blockIdx.y * 64;
  const int tx = tid & 15, ty = tid >> 4;
  const int lrow = tid >> 2, lg = tid & 3;
  const float* xp = x  + (size_t)(t0 + lrow) * HDIM + lg * 8;
  const float* gp = gw + (size_t)(e0 + lrow) * HDIM + lg * 8;
  float acc[4][4] = {};
  for (int k0 = 0; k0 < HDIM; k0 += 32) {
    f32x4 a = *(const f32x4*)(xp + k0);
    f32x4 b = *(const f32x4*)(xp + k0 + 4);
    f32x4 c = *(const f32x4*)(gp + k0);
    f32x4 d = *(const f32x4*)(gp + k0 + 4);
    __syncthreads();
    #pragma unroll
    for (int i = 0; i < 4; ++i) { xs[lrow][lg*8+i] = a[i]; xs[lrow][lg*8+4+i] = b[i]; }
    #pragma unroll
    for (int i = 0; i < 4; ++i) { gs[lrow][lg*8+i] = c[i]; gs[lrow][lg*8+4+i] = d[i]; }
    __syncthreads();
    #pragma unroll
    for (int k = 0; k < 32; ++k) {
      float av[4], bv[4];
      #pragma unroll
      for (int i = 0; i < 4; ++i) av[i] = xs[ty*4+i][k];
      #pragma unroll
      for (int j = 0; j < 4; ++j) bv[j] = gs[tx*4+j][k];
      #pragma unroll
      for (int i = 0; i < 4; ++i)
        #pragma unroll
        for (int j = 0; j < 4; ++j) acc[i][j] += av[i] * bv[j];
    }
  }
  #pragma unroll
  for (int i = 0; i < 4; ++i)
    #pragma unroll
    for (int j = 0; j < 4; ++j)
      logits[(size_t)(t0 + ty*4 + i) * NEXP + e0 + tx*4 + j] = acc[i][j];
}

// ---------------- top-8 + softmax + expert counts ----------------
__global__ __launch_bounds__(256) void topk_kernel(const float* __restrict__ logits,
                                                   int* __restrict__ tk_idx,
                                                   float* __restrict__ tk_w,
                                                   int* __restrict__ ctrl) {
  const int t = blockIdx.x * 4 + (threadIdx.x >> 6);
  const int lane = threadIdx.x & 63;
  const float* lp = logits + (size_t)t * NEXP;
  float v[4];
  #pragma unroll
  for (int j = 0; j < 4; ++j) v[j] = lp[lane + 64*j];
  float mval[8]; int midx[8];
  #pragma unroll
  for (int kk = 0; kk < 8; ++kk) {
    float bv = v[0]; int bj = 0;
    #pragma unroll
    for (int j = 1; j < 4; ++j) if (v[j] > bv) { bv = v[j]; bj = j; }
    unsigned int fb = __float_as_uint(bv);
    fb = (fb & 0x80000000u) ? ~fb : (fb | 0x80000000u);
    int e = lane + 64*bj;
    unsigned long long key = ((unsigned long long)fb << 32) | (unsigned int)(65535 - e);
    #pragma unroll
    for (int o = 32; o > 0; o >>= 1) {
      unsigned long long other = __shfl_xor(key, o);
      if (other > key) key = other;
    }
    int we = 65535 - (int)(key & 0xFFFFFFFFull);
    unsigned int wfb = (unsigned int)(key >> 32);
    unsigned int orig = (wfb & 0x80000000u) ? (wfb & 0x7FFFFFFFu) : ~wfb;
    mval[kk] = __uint_as_float(orig);
    midx[kk] = we;
    if (lane + 64*bj == we) v[bj] = -__builtin_inff();
  }
  float mx = mval[0];
  float w[8], sum = 0.f;
  #pragma unroll
  for (int kk = 0; kk < 8; ++kk) { w[kk] = __expf(mval[kk] - mx); sum += w[kk]; }
  float inv = 1.f / sum;
  #pragma unroll
  for (int kk = 0; kk < 8; ++kk) {
    if (lane == kk) {
      tk_idx[(size_t)t*8 + kk] = midx[kk];
      tk_w [(size_t)t*8 + kk] = w[kk] * inv;
      atomicAdd(&ctrl[midx[kk]], 1);
    }
  }
}

// ---------------- parallel scan + tile table ----------------
__global__ __launch_bounds__(256) void scan_kernel(int* __restrict__ ctrl, int* __restrict__ tiles) {
  __shared__ int sn[256], st[256];
  const int e = threadIdx.x;
  const int n = ctrl[e];
  const int tc = (n + 127) >> 7;
  sn[e] = n; st[e] = tc;
  __syncthreads();
  for (int d = 1; d < 256; d <<= 1) {
    int a = 0, b = 0;
    if (e >= d) { a = sn[e - d]; b = st[e - d]; }
    __syncthreads();
    sn[e] += a; st[e] += b;
    __syncthreads();
  }
  ctrl[1024 + e] = sn[e] - n;
  const int tbase = st[e] - tc;
  for (int i = 0; i < tc; ++i) { tiles[2*(tbase+i)] = e; tiles[2*(tbase+i)+1] = i << 7; }
  if (e == 255) { ctrl[512] = st[255]; ctrl[1280] = sn[255]; }
}

// ---------------- scatter (token,slot) -> grouped order ----------------
__global__ void scatter_kernel(const int* __restrict__ tk_idx, const float* __restrict__ tk_w,
                               int* __restrict__ ctrl, int* __restrict__ slot_tok,
                               float* __restrict__ slot_w, int* __restrict__ slot_pos) {
  int i = blockIdx.x * 256 + threadIdx.x;
  int e = tk_idx[i];
  int pos = ctrl[1024 + e] + atomicAdd(&ctrl[256 + e], 1);
  slot_tok[pos] = i >> 3;
  slot_w[pos]   = tk_w[i];
  slot_pos[i]   = pos;
}

// ---------------- grouped/dense SwiGLU, double-buffered single-barrier K-loop ----------------
template<bool GROUPED>
__global__ __launch_bounds__(256, 2)
void swiglu_kernel(const unsigned short* __restrict__ xb,
                   const float* __restrict__ W1b, const float* __restrict__ W3b,
                   const int N,
                   const int* __restrict__ ctrl, const int* __restrict__ tiles,
                   const int* __restrict__ slot_tok,
                   unsigned short* __restrict__ outH) {
  const int tid = threadIdx.x;
  const int b = xcdmap(blockIdx.x, gridDim.x);
  int e = 0, nrows = 128, rb, ncol0;
  if (GROUPED) {
    const int tIdx = b >> 2;
    ncol0 = (b & 3) << 7;
    if (tIdx >= ctrl[512]) return;
    e = tiles[2*tIdx];
    const int rowstart = tiles[2*tIdx + 1];
    nrows = min(128, ctrl[e] - rowstart);
    rb = ctrl[1024 + e] + rowstart;
  } else {
    ncol0 = (b >> 7) << 7;
    rb = (b & 127) << 7;
  }
  const size_t estride = (size_t)HDIM * N;
  const float* w1p = W1b + (GROUPED ? (size_t)e * estride : 0) + ncol0;
  const float* w3p = W3b + (GROUPED ? (size_t)e * estride : 0) + ncol0;

  __shared__ int tokArr[128];
  __shared__ unsigned short lX[2][128*32];
  __shared__ unsigned short lU[2][128*32];
  __shared__ unsigned short lV[2][128*32];

  if (tid < 128) {
    int r = min(tid, nrows - 1);
    tokArr[tid] = GROUPED ? slot_tok[rb + r] : (rb + tid);
  }
  __syncthreads();

  const int xrow0 = tid >> 2, xs0 = tid & 3;
  const int xrow1 = xrow0 + 64;
  const unsigned short* xptr0 = xb + (size_t)tokArr[xrow0] * HDIM + xs0 * 8;
  const unsigned short* xptr1 = xb + (size_t)tokArr[xrow1] * HDIM + xs0 * 8;
  const int kb4 = (tid >> 5) * 4;
  const int cb4 = (tid & 31) * 4;
  const float* upt = w1p + (size_t)kb4 * N + cb4;
  const float* vpt = w3p + (size_t)kb4 * N + cb4;

  const int lane = tid & 63, wid = tid >> 6;
  const int wr = (wid >> 1) * 64, wc = (wid & 1) * 64;
  const int lrow = lane & 15, lq = lane >> 4;

  // precomputed LDS offsets (element units)
  const int xw0 = xrow0*32 + ((xs0 ^ swzu(xrow0)) << 3);
  const int xw1 = xrow1*32 + ((xs0 ^ swzu(xrow1)) << 3);
  int wwo[4];
  #pragma unroll
  for (int j = 0; j < 4; ++j) {
    int col = cb4 + j;
    wwo[j] = col*32 + (((kb4 >> 3) ^ swzu(col)) << 3) + (kb4 & 7);
  }

  f32x4 aU[4][4], aV[4][4];
  #pragma unroll
  for (int i = 0; i < 4; ++i)
    #pragma unroll
    for (int j = 0; j < 4; ++j) { f32x4 z = {0.f,0.f,0.f,0.f}; aU[i][j] = z; aV[i][j] = z; }

  i32x4 xr0, xr1; f32x4 ur[4], vr[4];
  // prologue: load k-step 0, stage into buf0, prefetch k-step 1
  xr0 = *(const i32x4*)(xptr0);
  xr1 = *(const i32x4*)(xptr1);
  #pragma unroll
  for (int q = 0; q < 4; ++q) {
    ur[q] = *(const f32x4*)(upt + (size_t)q * N);
    vr[q] = *(const f32x4*)(vpt + (size_t)q * N);
  }
  *(i32x4*)&lX[0][xw0] = xr0;
  *(i32x4*)&lX[0][xw1] = xr1;
  #pragma unroll
  for (int j = 0; j < 4; ++j) {
    bf16x4v tu = { (__bf16)ur[0][j], (__bf16)ur[1][j], (__bf16)ur[2][j], (__bf16)ur[3][j] };
    bf16x4v tv = { (__bf16)vr[0][j], (__bf16)vr[1][j], (__bf16)vr[2][j], (__bf16)vr[3][j] };
    *(bf16x4v*)&lU[0][wwo[j]] = tu;
    *(bf16x4v*)&lV[0][wwo[j]] = tv;
  }
  {
    xr0 = *(const i32x4*)(xptr0 + 32);
    xr1 = *(const i32x4*)(xptr1 + 32);
    const float* uu = upt + (size_t)32 * N;
    const float* vv = vpt + (size_t)32 * N;
    #pragma unroll
    for (int q = 0; q < 4; ++q) {
      ur[q] = *(const f32x4*)(uu + (size_t)q * N);
      vr[q] = *(const f32x4*)(vv + (size_t)q * N);
    }
  }
  __syncthreads();

  #pragma unroll 1
  for (int ks = 0; ks < HDIM/32; ++ks) {
    const int cur = ks & 1;
    const unsigned short* bX = &lX[cur][0];
    const unsigned short* bU = &lU[cur][0];
    const unsigned short* bV = &lV[cur][0];
    bf16x8 af[4], bu[4], bv[4];
    #pragma unroll
    for (int i = 0; i < 4; ++i) {
      int row = wr + i*16 + lrow;
      af[i] = *(const bf16x8*)&bX[row*32 + ((lq ^ swzu(row)) << 3)];
    }
    #pragma unroll
    for (int j = 0; j < 4; ++j) {
      int col = wc + j*16 + lrow;
      int off = col*32 + ((lq ^ swzu(col)) << 3);
      bu[j] = *(const bf16x8*)&bU[off];
      bv[j] = *(const bf16x8*)&bV[off];
    }
    __builtin_amdgcn_s_setprio(1);
    #pragma unroll
    for (int i = 0; i < 4; ++i)
      #pragma unroll
      for (int j = 0; j < 4; ++j) {
        aU[i][j] = __builtin_amdgcn_mfma_f32_16x16x32_bf16(af[i], bu[j], aU[i][j], 0, 0, 0);
        aV[i][j] = __builtin_amdgcn_mfma_f32_16x16x32_bf16(af[i], bv[j], aV[i][j], 0, 0, 0);
      }
    __builtin_amdgcn_s_setprio(0);
    if (ks + 1 < HDIM/32) {
      // stage k-step ks+1 (already in regs) into the other buffer
      unsigned short* wX = &lX[cur ^ 1][0];
      unsigned short* wU = &lU[cur ^ 1][0];
      unsigned short* wV = &lV[cur ^ 1][0];
      *(i32x4*)&wX[xw0] = xr0;
      *(i32x4*)&wX[xw1] = xr1;
      #pragma unroll
      for (int j = 0; j < 4; ++j) {
        bf16x4v tu = { (__bf16)ur[0][j], (__bf16)ur[1][j], (__bf16)ur[2][j], (__bf16)ur[3][j] };
        bf16x4v tv = { (__bf16)vr[0][j], (__bf16)vr[1][j], (__bf16)vr[2][j], (__bf16)vr[3][j] };
        *(bf16x4v*)&wU[wwo[j]] = tu;
        *(bf16x4v*)&wV[wwo[j]] = tv;
      }
      if (ks + 2 < HDIM/32) {
        int k1 = (ks + 2) * 32;
        xr0 = *(const i32x4*)(xptr0 + k1);
        xr1 = *(const i32x4*)(xptr1 + k1);
        const float* uu = upt + (size_t)k1 * N;
        const float* vv = vpt + (size_t)k1 * N;
        #pragma unroll
        for (int q = 0; q < 4; ++q) {
          ur[q] = *(const f32x4*)(uu + (size_t)q * N);
          vr[q] = *(const f32x4*)(vv + (size_t)q * N);
        }
      }
      __syncthreads();
    }
  }
  #pragma unroll
  for (int i = 0; i < 4; ++i)
    #pragma unroll
    for (int j = 0; j < 4; ++j)
      #pragma unroll
      for (int r = 0; r < 4; ++r) {
        int rl = wr + i*16 + lq*4 + r;
        if (rl < nrows) {
          int col = ncol0 + wc + j*16 + lrow;
          float uu = aU[i][j][r], vv = aV[i][j][r];
          float sg = uu / (1.0f + __expf(-uu));
          ((__bf16*)outH)[(size_t)(rb + rl) * N + col] = (__bf16)(sg * vv);
        }
      }
}

// ---------------- grouped/dense GEMM2, double-buffered ----------------
template<bool GROUPED, bool F32OUT>
__global__ __launch_bounds__(256, 2)
void gemm2_kernel(const unsigned short* __restrict__ Asrc,
                  const float* __restrict__ Wb, const int K,
                  const int* __restrict__ ctrl, const int* __restrict__ tiles,
                  const float* __restrict__ slot_w,
                  unsigned short* __restrict__ outBF, float* __restrict__ outF) {
  const int tid = threadIdx.x;
  const int b = xcdmap(blockIdx.x, gridDim.x);
  int e = 0, nrows = 128, rb, ncol0;
  if (GROUPED) {
    const int tIdx = b >> 2;
    ncol0 = (b & 3) << 7;
    if (tIdx >= ctrl[512]) return;
    e = tiles[2*tIdx];
    const int rowstart = tiles[2*tIdx + 1];
    nrows = min(128, ctrl[e] - rowstart);
    rb = ctrl[1024 + e] + rowstart;
  } else {
    ncol0 = (b >> 7) << 7;
    rb = (b & 127) << 7;
  }
  const float* wp = Wb + (GROUPED ? (size_t)e * K * 512 : 0) + ncol0;

  __shared__ unsigned short lX[2][128*32];
  __shared__ unsigned short lW[2][128*32];

  const int xrow0 = tid >> 2, xs0 = tid & 3;
  const int xrow1 = xrow0 + 64;
  const unsigned short* xptr0 = Asrc + (size_t)(rb + min(xrow0, nrows-1)) * K + xs0 * 8;
  const unsigned short* xptr1 = Asrc + (size_t)(rb + min(xrow1, nrows-1)) * K + xs0 * 8;
  const int kb4 = (tid >> 5) * 4;
  const int cb4 = (tid & 31) * 4;
  const float* wpt = wp + (size_t)kb4 * 512 + cb4;

  const int lane = tid & 63, wid = tid >> 6;
  const int wr = (wid >> 1) * 64, wc = (wid & 1) * 64;
  const int lrow = lane & 15, lq = lane >> 4;

  const int xw0 = xrow0*32 + ((xs0 ^ swzu(xrow0)) << 3);
  const int xw1 = xrow1*32 + ((xs0 ^ swzu(xrow1)) << 3);
  int wwo[4];
  #pragma unroll
  for (int j = 0; j < 4; ++j) {
    int col = cb4 + j;
    wwo[j] = col*32 + (((kb4 >> 3) ^ swzu(col)) << 3) + (kb4 & 7);
  }

  f32x4 acc[4][4];
  #pragma unroll
  for (int i = 0; i < 4; ++i)
    #pragma unroll
    for (int j = 0; j < 4; ++j) { f32x4 z = {0.f,0.f,0.f,0.f}; acc[i][j] = z; }

  const int ksteps = K >> 5;
  i32x4 xr0, xr1; f32x4 wr4[4];
  xr0 = *(const i32x4*)(xptr0);
  xr1 = *(const i32x4*)(xptr1);
  #pragma unroll
  for (int q = 0; q < 4; ++q) wr4[q] = *(const f32x4*)(wpt + (size_t)q * 512);
  *(i32x4*)&lX[0][xw0] = xr0;
  *(i32x4*)&lX[0][xw1] = xr1;
  #pragma unroll
  for (int j = 0; j < 4; ++j) {
    bf16x4v tw = { (__bf16)wr4[0][j], (__bf16)wr4[1][j], (__bf16)wr4[2][j], (__bf16)wr4[3][j] };
    *(bf16x4v*)&lW[0][wwo[j]] = tw;
  }
  if (ksteps > 1) {
    xr0 = *(const i32x4*)(xptr0 + 32);
    xr1 = *(const i32x4*)(xptr1 + 32);
    const float* ww = wpt + (size_t)32 * 512;
    #pragma unroll
    for (int q = 0; q < 4; ++q) wr4[q] = *(const f32x4*)(ww + (size_t)q * 512);
  }
  __syncthreads();

  #pragma unroll 1
  for (int ks = 0; ks < ksteps; ++ks) {
    const int cur = ks & 1;
    const unsigned short* bX = &lX[cur][0];
    const unsigned short* bW = &lW[cur][0];
    bf16x8 af[4], bw[4];
    #pragma unroll
    for (int i = 0; i < 4; ++i) {
      int row = wr + i*16 + lrow;
      af[i] = *(const bf16x8*)&bX[row*32 + ((lq ^ swzu(row)) << 3)];
    }
    #pragma unroll
    for (int j = 0; j < 4; ++j) {
      int col = wc + j*16 + lrow;
      bw[j] = *(const bf16x8*)&bW[col*32 + ((lq ^ swzu(col)) << 3)];
    }
    __builtin_amdgcn_s_setprio(1);
    #pragma unroll
    for (int i = 0; i < 4; ++i)
      #pragma unroll
      for (int j = 0; j < 4; ++j)
        acc[i][j] = __builtin_amdgcn_mfma_f32_16x16x32_bf16(af[i], bw[j], acc[i][j], 0, 0, 0);
    __builtin_amdgcn_s_setprio(0);
    if (ks + 1 < ksteps) {
      unsigned short* wX = &lX[cur ^ 1][0];
      unsigned short* wW = &lW[cur ^ 1][0];
      *(i32x4*)&wX[xw0] = xr0;
      *(i32x4*)&wX[xw1] = xr1;
      #pragma unroll
      for (int j = 0; j < 4; ++j) {
        bf16x4v tw = { (__bf16)wr4[0][j], (__bf16)wr4[1][j], (__bf16)wr4[2][j], (__bf16)wr4[3][j] };
        *(bf16x4v*)&lW[cur ^ 1][wwo[j]] = tw;
      }
      (void)wW;
      if (ks + 2 < ksteps) {
        int k1 = (ks + 2) * 32;
        xr0 = *(const i32x4*)(xptr0 + k1);
        xr1 = *(const i32x4*)(xptr1 + k1);
        const float* ww = wpt + (size_t)k1 * 512;
        #pragma unroll
        for (int q = 0; q < 4; ++q) wr4[q] = *(const f32x4*)(ww + (size_t)q * 512);
      }
      __syncthreads();
    }
  }
  #pragma unroll
  for (int i = 0; i < 4; ++i)
    #pragma unroll
    for (int j = 0; j < 4; ++j)
      #pragma unroll
      for (int r = 0; r < 4; ++r) {
        int rl = wr + i*16 + lq*4 + r;
        if (rl < nrows) {
          int col = ncol0 + wc + j*16 + lrow;
          float v = acc[i][j][r];
          if (F32OUT) {
            outF[(size_t)(rb + rl) * 512 + col] = v;
          } else {
            ((__bf16*)outBF)[(size_t)(rb + rl) * 512 + col] = (__bf16)(v * slot_w[rb + rl]);
          }
        }
      }
}

// ---------------- combine ----------------
__global__ __launch_bounds__(256) void combine_kernel(const unsigned short* __restrict__ y_slot,
                                                      const int* __restrict__ slot_pos,
                                                      float* __restrict__ out) {
  const int t = blockIdx.x;
  const int h = threadIdx.x * 2;
  const int* sp = slot_pos + (size_t)t * 8;
  float a0 = 0.f, a1 = 0.f;
  #pragma unroll
  for (int k = 0; k < 8; ++k) {
    int row = sp[k];
    unsigned int u = *(const unsigned int*)(y_slot + (size_t)row * 512 + h);
    a0 += __uint_as_float(u << 16);
    a1 += __uint_as_float(u & 0xFFFF0000u);
  }
  size_t o = (size_t)t * 512 + h;
  out[o]     += a0;
  out[o + 1] += a1;
}

// ---------------- launch ----------------
extern "C" void kernel_launch(void* const* d_in, const int* in_sizes, int n_in,
                              void* d_out, int out_size, void* d_ws, size_t ws_size,
                              hipStream_t stream) {
  (void)in_sizes; (void)n_in; (void)out_size; (void)ws_size;
  const float* x    = (const float*)d_in[0];
  const float* gate = (const float*)d_in[1];
  const float* w1   = (const float*)d_in[2];
  const float* w3   = (const float*)d_in[3];
  const float* w2   = (const float*)d_in[4];
  const float* sw1  = (const float*)d_in[5];
  const float* sw3  = (const float*)d_in[6];
  const float* sw2  = (const float*)d_in[7];
  float* out = (float*)d_out;

  char* ws = (char*)d_ws;
  int*   ctrl     = (int*)ws;
  int*   tiles    = ctrl + 2048;
  int*   tk_idx   = (int*)  (ws + 32768);
  float* tk_w     = (float*)(ws + 32768 + 1*524288);
  int*   slot_tok = (int*)  (ws + 32768 + 2*524288);
  float* slot_w   = (float*)(ws + 32768 + 3*524288);
  int*   slot_pos = (int*)  (ws + 32768 + 4*524288);
  float* logits   = (float*)(ws + ((size_t)4  << 20));
  unsigned short* xb     = (unsigned short*)(ws + ((size_t)20 << 20));
  unsigned short* hid    = (unsigned short*)(ws + ((size_t)36 << 20));
  unsigned short* y_slot = (unsigned short*)(ws + ((size_t)36 << 20) + (size_t)134217728);
  unsigned short* hs     = (unsigned short*)(ws + ((size_t)36 << 20) + (size_t)2 * 134217728);

  hipMemsetAsync(d_ws, 0, 2052, stream);
  cast_kernel<<<4096, 256, 0, stream>>>(x, xb);
  router_kernel<<<dim3(256, 4), 256, 0, stream>>>(x, gate, logits);
  topk_kernel<<<4096, 256, 0, stream>>>(logits, tk_idx, tk_w, ctrl);
  scan_kernel<<<1, 256, 0, stream>>>(ctrl, tiles);
  scatter_kernel<<<512, 256, 0, stream>>>(tk_idx, tk_w, ctrl, slot_tok, slot_w, slot_pos);
  swiglu_kernel<true><<<5120, 256, 0, stream>>>(xb, w1, w3, 512, ctrl, tiles, slot_tok, hid);
  gemm2_kernel<true, false><<<5120, 256, 0, stream>>>(hid, w2, 512, ctrl, tiles, slot_w, y_slot, nullptr);
  swiglu_kernel<false><<<1408, 256, 0, stream>>>(xb, sw1, sw3, 1408, ctrl, tiles, slot_tok, hs);
  gemm2_kernel<false, true><<<512, 256, 0, stream>>>(hs, sw2, 1408, ctrl, tiles, slot_w, nullptr, out);
  combine_kernel<<<16384, 256, 0, stream>>>(y_slot, slot_pos, out);
}